// Round 14
// baseline (898.843 us; speedup 1.0000x reference)
//
#include <hip/hip_runtime.h>
#include <hip/hip_cooperative_groups.h>
#include <hip/hip_bf16.h>
#include <stdint.h>

namespace cg = cooperative_groups;

// GATv2 3-layer network. Round 13: cooperative mega-kernel, fixed launch.
// R12 failed with the zero-output signature => hipLaunchCooperativeKernel
// never ran (most likely grid > max co-resident; VGPR unbounded).
// Fixes: __launch_bounds__(256,3) pins 3 blocks/CU; grid sized from the
// occupancy API; launch return code checked with a deterministic fallback
// multi-dispatch path reusing the same __device__ stage bodies.

#define GAT_SLOPE 0.2f
#define ACT_SLOPE 0.01f
#define MAXDEG 64  // Poisson(16): P(deg>64) ~ 1e-18
#define TM 128
#define TN 128
#define TK 32

typedef _Float16 half8 __attribute__((ext_vector_type(8)));
typedef _Float16 v2h __attribute__((ext_vector_type(2)));
typedef float floatx4 __attribute__((ext_vector_type(4)));

struct MegaArgs {
  const float* W[6];
  _Float16* WT[6];
  int wK[6], wM[6], wOff[6];
  int wTotal;
  const float* nf;
  _Float16* A0;
  int aTotal;
  const int* src;
  const int* dst;
  int* counts;
  int* pcsrc;
  int E;
  float* dout;
  const _Float16* Ain[3];
  const _Float16* Bl[3];
  const _Float16* Br[3];
  _Float16* fs;
  _Float16* fd;
  _Float16* oh[2];
  const float* aw[3];
  const float* bias[3];
  int Kd[3], Md[3], tiles[3], nbxL[3];
  int nStrips;
  int N;
};

// ---------------- async global -> LDS (16B per lane) ----------------
__device__ __forceinline__ void gload_lds16(const _Float16* g, _Float16* l) {
  __builtin_amdgcn_global_load_lds(
      (__attribute__((address_space(1))) unsigned int*)g,
      (__attribute__((address_space(3))) unsigned int*)l, 16, 0, 0);
}

// ---------------- stage 0a: transposes + A0 cvt + zero counts/dout --------
__device__ void pre_stage(const MegaArgs& a) {
  const int total = a.wTotal + a.aTotal + a.N + 64;
  for (int i = blockIdx.x * 256 + threadIdx.x; i < total;
       i += gridDim.x * 256) {
    if (i < a.wTotal) {
      int q = 0;
#pragma unroll
      for (int j = 1; j < 6; ++j)
        if (i >= a.wOff[j]) q = j;
      int local = i - a.wOff[q];
      int K = a.wK[q], M = a.wM[q];
      int m = local / K, k = local % K;  // coalesced write, strided read
      a.WT[q][local] = (_Float16)a.W[q][(size_t)k * M + m];
    } else if (i < a.wTotal + a.aTotal) {
      int j = i - a.wTotal;
      a.A0[j] = (_Float16)a.nf[j];
    } else if (i < a.wTotal + a.aTotal + a.N) {
      a.counts[i - a.wTotal - a.aTotal] = 0;
    } else {
      a.dout[i - a.wTotal - a.aTotal - a.N] = 0.f;
    }
  }
}

// ---------------- stage 0b: padded-CSR atomic-append scatter --------------
__device__ void scatter_stage(const MegaArgs& a) {
  for (int e = blockIdx.x * 256 + threadIdx.x; e < a.E; e += gridDim.x * 256) {
    int d = a.dst[e];
    int pos = atomicAdd(&a.counts[d], 1);
    if (pos < MAXDEG) a.pcsrc[(size_t)d * MAXDEG + pos] = a.src[e];
  }
}

// ---------------- fp16 MFMA GEMM stage (persistent tile loop) -------------
__device__ void gemm_stage(const _Float16* __restrict__ A,
                           const _Float16* __restrict__ B0,
                           const _Float16* __restrict__ B1,
                           _Float16* __restrict__ C0, _Float16* __restrict__ C1,
                           int Nrow, int K, int M, int nStrips, int nbxLog2,
                           int totalTiles, _Float16* As, _Float16* Bs) {
  const int tid = threadIdx.x;
  const int w = tid >> 6;
  const int lane = tid & 63;
  const int wr = w >> 1;
  const int wc = w & 1;
  const int quad = lane >> 4;
  const int lr = lane & 15;
  const int lrow = lane >> 2;
  const int loff = (lane & 3) * 8;
  const int nbx = 1 << nbxLog2;
  const int nb = nbx >> 1;

  for (int T = blockIdx.x; T < totalTiles; T += gridDim.x) {
    const int xcd = T & 7;
    const int s = T >> 3;
    const int col = s & (nbx - 1);
    const int chunk = s >> nbxLog2;
    const int strip = chunk * 8 + xcd;
    if (strip >= nStrips) continue;  // block-uniform

    const bool second = col >= nb;
    const _Float16* B = second ? B1 : B0;
    _Float16* C = second ? C1 : C0;
    const int bn = (second ? col - nb : col) * TN;
    const int bm = strip * TM;

    floatx4 acc[4][4];
#pragma unroll
    for (int i = 0; i < 4; ++i)
#pragma unroll
      for (int j = 0; j < 4; ++j) acc[i][j] = (floatx4){0.f, 0.f, 0.f, 0.f};

    const int KT = K / TK;
    for (int kt = 0; kt < KT; ++kt) {
      const int k0 = kt * TK;
#pragma unroll
      for (int half = 0; half < 2; ++half) {
        const int r0 = w * 32 + half * 16;
        int ga = bm + r0 + lrow;
        if (ga >= Nrow) ga = Nrow - 1;
        gload_lds16(A + (size_t)ga * K + k0 + loff, As + r0 * TK);
        gload_lds16(B + (size_t)(bn + r0 + lrow) * K + k0 + loff,
                    Bs + r0 * TK);
      }
      __syncthreads();

      half8 ar[4], br[4];
#pragma unroll
      for (int i = 0; i < 4; ++i) {
        int row = wr * 64 + i * 16 + lr;
        ar[i] = *(const half8*)(As + row * TK + quad * 8);
      }
#pragma unroll
      for (int j = 0; j < 4; ++j) {
        int colr = wc * 64 + j * 16 + lr;
        br[j] = *(const half8*)(Bs + colr * TK + quad * 8);
      }
#pragma unroll
      for (int i = 0; i < 4; ++i)
#pragma unroll
        for (int j = 0; j < 4; ++j)
          acc[i][j] = __builtin_amdgcn_mfma_f32_16x16x32_f16(
              ar[i], br[j], acc[i][j], 0, 0, 0);
      __syncthreads();
    }

#pragma unroll
    for (int i = 0; i < 4; ++i) {
#pragma unroll
      for (int r = 0; r < 4; ++r) {
        int row = bm + wr * 64 + i * 16 + quad * 4 + r;
        if (row >= Nrow) continue;
#pragma unroll
        for (int j = 0; j < 4; ++j) {
          int colc = bn + wc * 64 + j * 16 + lr;
          C[(size_t)row * M + colc] = (_Float16)acc[i][j][r];
        }
      }
    }
  }
}

// ---------------- attn stage: 1 wave/node, 4 nodes/block, padded CSR ------
template <int D, bool LAST>
__device__ void attn_stage(const _Float16* __restrict__ fs,
                           const _Float16* __restrict__ fd,
                           const int* __restrict__ counts,
                           const int* __restrict__ pcsrc,
                           const float* __restrict__ aw,
                           const float* __restrict__ bias,
                           _Float16* __restrict__ oh, float* __restrict__ dout,
                           int N, float* facc) {
  constexpr int HD = 4 * D;
  constexpr int R = HD / 64;
  constexpr int R2 = R / 2;
  typedef _Float16 halfR __attribute__((ext_vector_type(R)));
  union Frag {
    halfR v;
    v2h h[R2];
    _Float16 s[R];
  };
  const int wid = threadIdx.x >> 6;
  const int lane = threadIdx.x & 63;
  const v2h slope2 = {(_Float16)GAT_SLOPE, (_Float16)GAT_SLOPE};

  if (LAST) {
    if (threadIdx.x < 64) facc[threadIdx.x] = 0.f;
    __syncthreads();
  }

  v2h ar2[R2];
#pragma unroll
  for (int j = 0; j < R2; ++j) {
    ar2[j][0] = (_Float16)aw[lane * R + 2 * j];
    ar2[j][1] = (_Float16)aw[lane * R + 2 * j + 1];
  }
  float br[R];
#pragma unroll
  for (int i = 0; i < R; ++i) br[i] = bias[lane * R + i];

  for (int v0 = blockIdx.x * 4; v0 < N; v0 += gridDim.x * 4) {
    const int v = v0 + wid;
    if (v < N) {
      Frag fdv;
      fdv.v = *(const halfR*)(fd + (size_t)v * HD + lane * R);
      float m = -INFINITY, l = 0.f;
      float O[R];
#pragma unroll
      for (int i = 0; i < R; ++i) O[i] = 0.f;

      const int cnt = min(counts[v], MAXDEG);
      const int* elist = pcsrc + (size_t)v * MAXDEG;
      int k = 0;
      for (; k + 3 < cnt; k += 4) {
        const int s0 = elist[k];
        const int s1 = elist[k + 1];
        const int s2 = elist[k + 2];
        const int s3 = elist[k + 3];
        Frag t0, t1, t2, t3;
        t0.v = *(const halfR*)(fs + (size_t)s0 * HD + lane * R);
        t1.v = *(const halfR*)(fs + (size_t)s1 * HD + lane * R);
        t2.v = *(const halfR*)(fs + (size_t)s2 * HD + lane * R);
        t3.v = *(const halfR*)(fs + (size_t)s3 * HD + lane * R);
        float p0 = 0.f, p1 = 0.f, p2 = 0.f, p3 = 0.f;
#pragma unroll
        for (int j = 0; j < R2; ++j) {
          v2h x0 = t0.h[j] + fdv.h[j];
          v2h x1 = t1.h[j] + fdv.h[j];
          v2h x2 = t2.h[j] + fdv.h[j];
          v2h x3 = t3.h[j] + fdv.h[j];
          x0 = __builtin_elementwise_max(x0, x0 * slope2);
          x1 = __builtin_elementwise_max(x1, x1 * slope2);
          x2 = __builtin_elementwise_max(x2, x2 * slope2);
          x3 = __builtin_elementwise_max(x3, x3 * slope2);
          p0 = __builtin_amdgcn_fdot2(ar2[j], x0, p0, false);
          p1 = __builtin_amdgcn_fdot2(ar2[j], x1, p1, false);
          p2 = __builtin_amdgcn_fdot2(ar2[j], x2, p2, false);
          p3 = __builtin_amdgcn_fdot2(ar2[j], x3, p3, false);
        }
#pragma unroll
        for (int off = 1; off <= 8; off <<= 1) {
          p0 += __shfl_xor(p0, off, 64);
          p1 += __shfl_xor(p1, off, 64);
          p2 += __shfl_xor(p2, off, 64);
          p3 += __shfl_xor(p3, off, 64);
        }
        const float mq = fmaxf(fmaxf(p0, p1), fmaxf(p2, p3));
        const float w0 = __expf(p0 - mq);
        const float w1 = __expf(p1 - mq);
        const float w2 = __expf(p2 - mq);
        const float w3 = __expf(p3 - mq);
        const float mnew = fmaxf(m, mq);
        const float sc = __expf(m - mnew);
        const float sq = __expf(mq - mnew);
        l = l * sc + (w0 + w1 + w2 + w3) * sq;
#pragma unroll
        for (int i = 0; i < R; ++i) {
          float acc = (float)t0.s[i] * w0;
          acc = fmaf((float)t1.s[i], w1, acc);
          acc = fmaf((float)t2.s[i], w2, acc);
          acc = fmaf((float)t3.s[i], w3, acc);
          O[i] = fmaf(O[i], sc, sq * acc);
        }
        m = mnew;
      }
      for (; k < cnt; ++k) {
        const int s0 = elist[k];
        Frag t0;
        t0.v = *(const halfR*)(fs + (size_t)s0 * HD + lane * R);
        float p0 = 0.f;
#pragma unroll
        for (int j = 0; j < R2; ++j) {
          v2h x0 = t0.h[j] + fdv.h[j];
          x0 = __builtin_elementwise_max(x0, x0 * slope2);
          p0 = __builtin_amdgcn_fdot2(ar2[j], x0, p0, false);
        }
#pragma unroll
        for (int off = 1; off <= 8; off <<= 1) p0 += __shfl_xor(p0, off, 64);
        const float mnew = fmaxf(m, p0);
        const float sc = __expf(m - mnew);
        const float p = __expf(p0 - mnew);
        l = l * sc + p;
#pragma unroll
        for (int i = 0; i < R; ++i) O[i] = fmaf(O[i], sc, p * (float)t0.s[i]);
        m = mnew;
      }

      const float inv = (l > 0.f) ? 1.f / l : 0.f;
#pragma unroll
      for (int i = 0; i < R; ++i) O[i] = O[i] * inv + br[i];
#pragma unroll
      for (int i = 0; i < R; ++i) {
        O[i] += __shfl_xor(O[i], 16, 64);
        O[i] += __shfl_xor(O[i], 32, 64);
        float x = O[i] * 0.25f;
        O[i] = x > 0.f ? x : x * ACT_SLOPE;
      }
      if (lane < 16) {
        if (!LAST) {
          const size_t base = (size_t)v * D + lane * R;
#pragma unroll
          for (int i = 0; i < R; ++i) oh[base + i] = (_Float16)O[i];
        } else {
#pragma unroll
          for (int i = 0; i < R; ++i) atomicAdd(&facc[lane * R + i], O[i]);
        }
      }
    }
  }

  if (LAST) {
    __syncthreads();
    if (threadIdx.x < 64)
      atomicAdd(&dout[threadIdx.x], facc[threadIdx.x] / (float)N);
  }
}

// ---------------- the mega kernel (cooperative) ----------------
__global__ __launch_bounds__(256, 3) void mega_kernel(MegaArgs a) {
  cg::grid_group grid = cg::this_grid();
  __shared__ __align__(16) _Float16 As[TM * TK];
  __shared__ __align__(16) _Float16 Bs[TN * TK];

  pre_stage(a);
  grid.sync();
  scatter_stage(a);
  grid.sync();

  float* facc = (float*)As;

  gemm_stage(a.Ain[0], a.Bl[0], a.Br[0], a.fs, a.fd, a.N, a.Kd[0], a.Md[0],
             a.nStrips, a.nbxL[0], a.tiles[0], As, Bs);
  grid.sync();
  attn_stage<128, false>(a.fs, a.fd, a.counts, a.pcsrc, a.aw[0], a.bias[0],
                         a.oh[0], nullptr, a.N, nullptr);
  grid.sync();
  gemm_stage(a.Ain[1], a.Bl[1], a.Br[1], a.fs, a.fd, a.N, a.Kd[1], a.Md[1],
             a.nStrips, a.nbxL[1], a.tiles[1], As, Bs);
  grid.sync();
  attn_stage<128, false>(a.fs, a.fd, a.counts, a.pcsrc, a.aw[1], a.bias[1],
                         a.oh[1], nullptr, a.N, nullptr);
  grid.sync();
  gemm_stage(a.Ain[2], a.Bl[2], a.Br[2], a.fs, a.fd, a.N, a.Kd[2], a.Md[2],
             a.nStrips, a.nbxL[2], a.tiles[2], As, Bs);
  grid.sync();
  attn_stage<64, true>(a.fs, a.fd, a.counts, a.pcsrc, a.aw[2], a.bias[2],
                       nullptr, a.dout, a.N, facc);
}

// ---------------- fallback wrappers (separate dispatches) ----------------
__global__ __launch_bounds__(256) void pre_kernel(MegaArgs a) { pre_stage(a); }
__global__ __launch_bounds__(256) void scatter_kernel(MegaArgs a) {
  scatter_stage(a);
}
__global__ __launch_bounds__(256) void gemm_fb_kernel(
    const _Float16* A, const _Float16* B0, const _Float16* B1, _Float16* C0,
    _Float16* C1, int Nrow, int K, int M, int nStrips, int nbxLog2,
    int totalTiles) {
  __shared__ __align__(16) _Float16 As[TM * TK];
  __shared__ __align__(16) _Float16 Bs[TN * TK];
  gemm_stage(A, B0, B1, C0, C1, Nrow, K, M, nStrips, nbxLog2, totalTiles, As,
             Bs);
}
template <int D, bool LAST>
__global__ __launch_bounds__(256) void attn_fb_kernel(
    const _Float16* fs, const _Float16* fd, const int* counts,
    const int* pcsrc, const float* aw, const float* bias, _Float16* oh,
    float* dout, int N) {
  __shared__ float facc[64];
  attn_stage<D, LAST>(fs, fd, counts, pcsrc, aw, bias, oh, dout, N, facc);
}

// ------------------------------------------------------------------
extern "C" void kernel_launch(void* const* d_in, const int* in_sizes, int n_in,
                              void* d_out, int out_size, void* d_ws,
                              size_t ws_size, hipStream_t stream) {
  const float* n_feat = (const float*)d_in[0];
  const int* src = (const int*)d_in[1];
  const int* dst = (const int*)d_in[2];
  const float* Wl[3] = {(const float*)d_in[3], (const float*)d_in[7],
                        (const float*)d_in[11]};
  const float* Wr[3] = {(const float*)d_in[4], (const float*)d_in[8],
                        (const float*)d_in[12]};
  const float* attnw[3] = {(const float*)d_in[5], (const float*)d_in[9],
                           (const float*)d_in[13]};
  const float* bias[3] = {(const float*)d_in[6], (const float*)d_in[10],
                          (const float*)d_in[14]};

  const int N = in_sizes[0] / 512;  // 20000
  const int E = in_sizes[1];        // 320000
  const int Kdim[3] = {512, 128, 128};
  const int Mdim[3] = {512, 512, 256};

  char* ws = (char*)d_ws;
  size_t o = 0;
  auto alloc = [&](size_t bytes) {
    void* p = ws + o;
    o += (bytes + 15) & ~(size_t)15;
    return p;
  };
  _Float16* fs = (_Float16*)alloc((size_t)N * 512 * 2);
  _Float16* fd = (_Float16*)alloc((size_t)N * 512 * 2);
  _Float16* A0 = (_Float16*)alloc((size_t)N * 512 * 2);
  _Float16* h1 = (_Float16*)alloc((size_t)N * 128 * 2);
  _Float16* h2 = (_Float16*)alloc((size_t)N * 128 * 2);
  _Float16* WT[6];
  for (int L = 0; L < 3; ++L) {
    size_t sz = (size_t)Kdim[L] * Mdim[L] * 2;
    WT[2 * L] = (_Float16*)alloc(sz);
    WT[2 * L + 1] = (_Float16*)alloc(sz);
  }
  int* counts = (int*)alloc((size_t)N * 4);
  int* pcsrc = (int*)alloc((size_t)N * MAXDEG * 4);

  MegaArgs a;
  {
    int off = 0;
    for (int L = 0; L < 3; ++L) {
      a.W[2 * L] = Wl[L];
      a.W[2 * L + 1] = Wr[L];
      a.WT[2 * L] = WT[2 * L];
      a.WT[2 * L + 1] = WT[2 * L + 1];
      a.wK[2 * L] = a.wK[2 * L + 1] = Kdim[L];
      a.wM[2 * L] = a.wM[2 * L + 1] = Mdim[L];
      a.wOff[2 * L] = off;
      off += Kdim[L] * Mdim[L];
      a.wOff[2 * L + 1] = off;
      off += Kdim[L] * Mdim[L];
    }
    a.wTotal = off;
  }
  a.nf = n_feat;
  a.A0 = A0;
  a.aTotal = N * 512;
  a.src = src;
  a.dst = dst;
  a.counts = counts;
  a.pcsrc = pcsrc;
  a.E = E;
  a.dout = (float*)d_out;
  a.Ain[0] = A0;
  a.Ain[1] = h1;
  a.Ain[2] = h2;
  for (int L = 0; L < 3; ++L) {
    a.Bl[L] = WT[2 * L];
    a.Br[L] = WT[2 * L + 1];
    a.Kd[L] = Kdim[L];
    a.Md[L] = Mdim[L];
    a.aw[L] = attnw[L];
    a.bias[L] = bias[L];
  }
  a.fs = fs;
  a.fd = fd;
  a.oh[0] = h1;
  a.oh[1] = h2;
  a.nStrips = (N + TM - 1) / TM;             // 157
  const int S8 = ((a.nStrips + 7) / 8) * 8;  // 160
  a.nbxL[0] = 3;
  a.nbxL[1] = 3;
  a.nbxL[2] = 2;
  a.tiles[0] = S8 * 8;
  a.tiles[1] = S8 * 8;
  a.tiles[2] = S8 * 4;
  a.N = N;

  auto run_fallback = [&]() {
    int totalPre = a.wTotal + a.aTotal + a.N + 64;
    pre_kernel<<<(totalPre + 255) / 256, 256, 0, stream>>>(a);
    scatter_kernel<<<(E + 255) / 256, 256, 0, stream>>>(a);
    for (int L = 0; L < 3; ++L) {
      gemm_fb_kernel<<<a.tiles[L], 256, 0, stream>>>(
          a.Ain[L], a.Bl[L], a.Br[L], fs, fd, N, a.Kd[L], a.Md[L], a.nStrips,
          a.nbxL[L], a.tiles[L]);
      if (L == 0) {
        attn_fb_kernel<128, false><<<(N + 3) / 4, 256, 0, stream>>>(
            fs, fd, counts, pcsrc, a.aw[0], a.bias[0], h1, nullptr, N);
      } else if (L == 1) {
        attn_fb_kernel<128, false><<<(N + 3) / 4, 256, 0, stream>>>(
            fs, fd, counts, pcsrc, a.aw[1], a.bias[1], h2, nullptr, N);
      } else {
        attn_fb_kernel<64, true><<<(N + 3) / 4, 256, 0, stream>>>(
            fs, fd, counts, pcsrc, a.aw[2], a.bias[2], nullptr, (float*)d_out,
            N);
      }
    }
  };

  // Capability + occupancy-sized cooperative launch, else fallback.
  int dev = 0;
  (void)hipGetDevice(&dev);
  int coopAttr = 0;
  (void)hipDeviceGetAttribute(&coopAttr, hipDeviceAttributeCooperativeLaunch,
                              dev);
  int occ = 0;
  hipError_t oe =
      hipOccupancyMaxActiveBlocksPerMultiprocessor(&occ, mega_kernel, 256, 0);
  int nblk = 0;
  if (oe == hipSuccess && occ > 0) {
    nblk = occ * 256;            // 256 CUs on MI355X
    if (nblk > 768) nblk = 768;  // cap: diminishing returns past 3 blk/CU
    nblk &= ~7;                  // multiple of 8 for XCD affinity
  }
  bool launched = false;
  if (coopAttr && nblk >= 8) {
    void* params[] = {&a};
    hipError_t le = hipLaunchCooperativeKernel(mega_kernel, dim3(nblk),
                                               dim3(256), params, 0, stream);
    launched = (le == hipSuccess);
  }
  if (!launched) run_fallback();
}

// Round 15
// 359.376 us; speedup vs baseline: 2.5011x; 2.5011x over previous
//
#include <hip/hip_runtime.h>
#include <hip/hip_bf16.h>
#include <stdint.h>

// GATv2 3-layer network. Round 14: revert cooperative mega-kernel (R13:
// grid.sync costs ~100us on 8 non-coherent XCDs -> 899us total). Back to the
// R12 multi-dispatch pipeline (358us) minus two graph nodes:
//   - d_out zeroing folded into preproc
//   - final node-mean folded into attn layer 2 (persistent blocks + LDS
//     accumulator + one 64-float atomic flush per block)
// 8 graph nodes total: memset(counts), preproc, 3x(gemm, attn).
// GEMM: fp16 MFMA dual-B, XCD-affinity swizzle, global_load_lds staging.
// attn: 4 nodes/block, packed-fp16 (v_pk_* + v_dot2_f32_f16 + fma_mix),
// padded CSR. attn is at its L2/fabric fill floor (~53us/layer, verified
// R8/R9/R12 invariance).

#define GAT_SLOPE 0.2f
#define ACT_SLOPE 0.01f
#define MAXDEG 64  // Poisson(16): P(deg>64) ~ 1e-18
#define TM 128
#define TN 128
#define TK 32

typedef _Float16 half8 __attribute__((ext_vector_type(8)));
typedef _Float16 v2h __attribute__((ext_vector_type(2)));
typedef float floatx4 __attribute__((ext_vector_type(4)));

// ---------------- fused preprocessing ----------------
// (1) 6 weight transposes fp32->fp16 [M][K] (coalesced writes),
// (2) layer-0 input fp32->fp16, (3) zero d_out, (4) padded-CSR scatter.
// counts zeroed by a preceding hipMemsetAsync (R12-verified ordering).
struct PreArgs {
  const float* W[6];
  _Float16* WT[6];
  int wK[6], wM[6], wOff[6];
  int wTotal;
  const float* nf;
  _Float16* A0;
  int aTotal;
  const int* src;
  const int* dst;
  int* counts;
  int* pcsrc;
  int E;
  float* dout;
};

__global__ __launch_bounds__(256) void preproc_kernel(PreArgs pa) {
  int i = blockIdx.x * 256 + threadIdx.x;
  const int total = pa.wTotal + pa.aTotal + 64 + pa.E;
  if (i >= total) return;
  if (i < pa.wTotal) {
    int q = 0;
#pragma unroll
    for (int j = 1; j < 6; ++j)
      if (i >= pa.wOff[j]) q = j;
    int local = i - pa.wOff[q];
    int K = pa.wK[q], M = pa.wM[q];
    int m = local / K, k = local % K;  // coalesced write, L2-absorbed read
    pa.WT[q][local] = (_Float16)pa.W[q][(size_t)k * M + m];
  } else if (i < pa.wTotal + pa.aTotal) {
    int j = i - pa.wTotal;
    pa.A0[j] = (_Float16)pa.nf[j];
  } else if (i < pa.wTotal + pa.aTotal + 64) {
    pa.dout[i - pa.wTotal - pa.aTotal] = 0.f;
  } else {
    int e = i - pa.wTotal - pa.aTotal - 64;
    int d = pa.dst[e];
    int pos = atomicAdd(&pa.counts[d], 1);
    if (pos < MAXDEG) pa.pcsrc[(size_t)d * MAXDEG + pos] = pa.src[e];
  }
}

// ---------------- async global -> LDS (16B per lane) ----------------
__device__ __forceinline__ void gload_lds16(const _Float16* g, _Float16* l) {
  __builtin_amdgcn_global_load_lds(
      (__attribute__((address_space(1))) unsigned int*)g,
      (__attribute__((address_space(3))) unsigned int*)l, 16, 0, 0);
}

// ---------------- fp16 MFMA GEMM, dual-B, fp16 output ----------------
__global__ __launch_bounds__(256) void gemm_mfma_dual_kernel(
    const _Float16* __restrict__ A, const _Float16* __restrict__ B0,
    const _Float16* __restrict__ B1, _Float16* __restrict__ C0,
    _Float16* __restrict__ C1, int Nrow, int K, int M, int nStrips,
    int nbxLog2) {
  const int id = blockIdx.x;
  const int xcd = id & 7;
  const int s = id >> 3;
  const int nbx = 1 << nbxLog2;
  const int col = s & (nbx - 1);
  const int chunk = s >> nbxLog2;
  const int strip = chunk * 8 + xcd;
  if (strip >= nStrips) return;

  const int nb = nbx >> 1;
  const bool second = col >= nb;
  const _Float16* B = second ? B1 : B0;
  _Float16* C = second ? C1 : C0;
  const int bn = (second ? col - nb : col) * TN;
  const int bm = strip * TM;

  __shared__ __align__(16) _Float16 As[TM * TK];
  __shared__ __align__(16) _Float16 Bs[TN * TK];

  const int tid = threadIdx.x;
  const int w = tid >> 6;
  const int lane = tid & 63;
  const int wr = w >> 1;
  const int wc = w & 1;
  const int quad = lane >> 4;
  const int lr = lane & 15;
  const int lrow = lane >> 2;
  const int loff = (lane & 3) * 8;

  floatx4 acc[4][4];
#pragma unroll
  for (int i = 0; i < 4; ++i)
#pragma unroll
    for (int j = 0; j < 4; ++j) acc[i][j] = (floatx4){0.f, 0.f, 0.f, 0.f};

  const int KT = K / TK;
  for (int kt = 0; kt < KT; ++kt) {
    const int k0 = kt * TK;
#pragma unroll
    for (int half = 0; half < 2; ++half) {
      const int r0 = w * 32 + half * 16;
      int ga = bm + r0 + lrow;
      if (ga >= Nrow) ga = Nrow - 1;  // clamp; clamped outputs discarded
      gload_lds16(A + (size_t)ga * K + k0 + loff, As + r0 * TK);
      gload_lds16(B + (size_t)(bn + r0 + lrow) * K + k0 + loff, Bs + r0 * TK);
    }
    __syncthreads();

    half8 ar[4], br[4];
#pragma unroll
    for (int i = 0; i < 4; ++i) {
      int row = wr * 64 + i * 16 + lr;
      ar[i] = *(const half8*)(As + row * TK + quad * 8);
    }
#pragma unroll
    for (int j = 0; j < 4; ++j) {
      int colr = wc * 64 + j * 16 + lr;
      br[j] = *(const half8*)(Bs + colr * TK + quad * 8);
    }
#pragma unroll
    for (int i = 0; i < 4; ++i)
#pragma unroll
      for (int j = 0; j < 4; ++j)
        acc[i][j] = __builtin_amdgcn_mfma_f32_16x16x32_f16(ar[i], br[j],
                                                           acc[i][j], 0, 0, 0);
    __syncthreads();
  }

  // epilogue: C/D layout col=lane&15, row=quad*4+reg
#pragma unroll
  for (int i = 0; i < 4; ++i) {
#pragma unroll
    for (int r = 0; r < 4; ++r) {
      int row = bm + wr * 64 + i * 16 + quad * 4 + r;
      if (row >= Nrow) continue;
#pragma unroll
      for (int j = 0; j < 4; ++j) {
        int colc = bn + wc * 64 + j * 16 + lr;
        C[(size_t)row * M + colc] = (_Float16)acc[i][j][r];
      }
    }
  }
}

// ---------------- fused per-node GATv2 attention ----------------
// 4 nodes/block (1 wave each), padded CSR, packed-fp16 math.
// LAST: persistent node loop + LDS accumulator + 1 atomic flush per block
// (folds the final per-graph mean readout into this kernel).
template <int D, bool LAST>
__global__ __launch_bounds__(256) void node_attn_kernel(
    const _Float16* __restrict__ fs, const _Float16* __restrict__ fd,
    const int* __restrict__ counts, const int* __restrict__ pcsrc,
    const float* __restrict__ aw, const float* __restrict__ bias,
    _Float16* __restrict__ oh, float* __restrict__ dout, int N) {
  constexpr int HD = 4 * D;
  constexpr int R = HD / 64;
  constexpr int R2 = R / 2;
  typedef _Float16 halfR __attribute__((ext_vector_type(R)));
  union Frag {
    halfR v;
    v2h h[R2];
    _Float16 s[R];
  };
  __shared__ float facc[64];
  const int wid = threadIdx.x >> 6;
  const int lane = threadIdx.x & 63;
  const v2h slope2 = {(_Float16)GAT_SLOPE, (_Float16)GAT_SLOPE};

  if (LAST) {
    if (threadIdx.x < 64) facc[threadIdx.x] = 0.f;
    __syncthreads();
  }

  v2h ar2[R2];
#pragma unroll
  for (int j = 0; j < R2; ++j) {
    ar2[j][0] = (_Float16)aw[lane * R + 2 * j];
    ar2[j][1] = (_Float16)aw[lane * R + 2 * j + 1];
  }
  float br[R];
#pragma unroll
  for (int i = 0; i < R; ++i) br[i] = bias[lane * R + i];

  for (int v0 = blockIdx.x * 4; v0 < N; v0 += gridDim.x * 4) {
    const int v = v0 + wid;
    if (v < N) {
      Frag fdv;
      fdv.v = *(const halfR*)(fd + (size_t)v * HD + lane * R);
      float m = -INFINITY, l = 0.f;
      float O[R];
#pragma unroll
      for (int i = 0; i < R; ++i) O[i] = 0.f;

      const int cnt = min(counts[v], MAXDEG);
      const int* elist = pcsrc + (size_t)v * MAXDEG;
      int k = 0;
      for (; k + 3 < cnt; k += 4) {
        const int s0 = elist[k];
        const int s1 = elist[k + 1];
        const int s2 = elist[k + 2];
        const int s3 = elist[k + 3];
        Frag t0, t1, t2, t3;
        t0.v = *(const halfR*)(fs + (size_t)s0 * HD + lane * R);
        t1.v = *(const halfR*)(fs + (size_t)s1 * HD + lane * R);
        t2.v = *(const halfR*)(fs + (size_t)s2 * HD + lane * R);
        t3.v = *(const halfR*)(fs + (size_t)s3 * HD + lane * R);
        float p0 = 0.f, p1 = 0.f, p2 = 0.f, p3 = 0.f;
#pragma unroll
        for (int j = 0; j < R2; ++j) {
          v2h x0 = t0.h[j] + fdv.h[j];
          v2h x1 = t1.h[j] + fdv.h[j];
          v2h x2 = t2.h[j] + fdv.h[j];
          v2h x3 = t3.h[j] + fdv.h[j];
          x0 = __builtin_elementwise_max(x0, x0 * slope2);
          x1 = __builtin_elementwise_max(x1, x1 * slope2);
          x2 = __builtin_elementwise_max(x2, x2 * slope2);
          x3 = __builtin_elementwise_max(x3, x3 * slope2);
          p0 = __builtin_amdgcn_fdot2(ar2[j], x0, p0, false);
          p1 = __builtin_amdgcn_fdot2(ar2[j], x1, p1, false);
          p2 = __builtin_amdgcn_fdot2(ar2[j], x2, p2, false);
          p3 = __builtin_amdgcn_fdot2(ar2[j], x3, p3, false);
        }
#pragma unroll
        for (int off = 1; off <= 8; off <<= 1) {
          p0 += __shfl_xor(p0, off, 64);
          p1 += __shfl_xor(p1, off, 64);
          p2 += __shfl_xor(p2, off, 64);
          p3 += __shfl_xor(p3, off, 64);
        }
        const float mq = fmaxf(fmaxf(p0, p1), fmaxf(p2, p3));
        const float w0 = __expf(p0 - mq);
        const float w1 = __expf(p1 - mq);
        const float w2 = __expf(p2 - mq);
        const float w3 = __expf(p3 - mq);
        const float mnew = fmaxf(m, mq);
        const float sc = __expf(m - mnew);
        const float sq = __expf(mq - mnew);
        l = l * sc + (w0 + w1 + w2 + w3) * sq;
#pragma unroll
        for (int i = 0; i < R; ++i) {
          float acc = (float)t0.s[i] * w0;
          acc = fmaf((float)t1.s[i], w1, acc);
          acc = fmaf((float)t2.s[i], w2, acc);
          acc = fmaf((float)t3.s[i], w3, acc);
          O[i] = fmaf(O[i], sc, sq * acc);
        }
        m = mnew;
      }
      for (; k < cnt; ++k) {
        const int s0 = elist[k];
        Frag t0;
        t0.v = *(const halfR*)(fs + (size_t)s0 * HD + lane * R);
        float p0 = 0.f;
#pragma unroll
        for (int j = 0; j < R2; ++j) {
          v2h x0 = t0.h[j] + fdv.h[j];
          x0 = __builtin_elementwise_max(x0, x0 * slope2);
          p0 = __builtin_amdgcn_fdot2(ar2[j], x0, p0, false);
        }
#pragma unroll
        for (int off = 1; off <= 8; off <<= 1) p0 += __shfl_xor(p0, off, 64);
        const float mnew = fmaxf(m, p0);
        const float sc = __expf(m - mnew);
        const float p = __expf(p0 - mnew);
        l = l * sc + p;
#pragma unroll
        for (int i = 0; i < R; ++i) O[i] = fmaf(O[i], sc, p * (float)t0.s[i]);
        m = mnew;
      }

      const float inv = (l > 0.f) ? 1.f / l : 0.f;
#pragma unroll
      for (int i = 0; i < R; ++i) O[i] = O[i] * inv + br[i];
#pragma unroll
      for (int i = 0; i < R; ++i) {
        O[i] += __shfl_xor(O[i], 16, 64);
        O[i] += __shfl_xor(O[i], 32, 64);
        float x = O[i] * 0.25f;
        O[i] = x > 0.f ? x : x * ACT_SLOPE;
      }
      if (lane < 16) {
        if (!LAST) {
          const size_t base = (size_t)v * D + lane * R;
#pragma unroll
          for (int i = 0; i < R; ++i) oh[base + i] = (_Float16)O[i];
        } else {
#pragma unroll
          for (int i = 0; i < R; ++i) atomicAdd(&facc[lane * R + i], O[i]);
        }
      }
    }
  }

  if (LAST) {
    __syncthreads();
    if (threadIdx.x < 64)
      atomicAdd(&dout[threadIdx.x], facc[threadIdx.x] / (float)N);
  }
}

// ------------------------------------------------------------------
extern "C" void kernel_launch(void* const* d_in, const int* in_sizes, int n_in,
                              void* d_out, int out_size, void* d_ws,
                              size_t ws_size, hipStream_t stream) {
  const float* n_feat = (const float*)d_in[0];
  const int* src = (const int*)d_in[1];
  const int* dst = (const int*)d_in[2];
  const float* Wl[3] = {(const float*)d_in[3], (const float*)d_in[7],
                        (const float*)d_in[11]};
  const float* Wr[3] = {(const float*)d_in[4], (const float*)d_in[8],
                        (const float*)d_in[12]};
  const float* attnw[3] = {(const float*)d_in[5], (const float*)d_in[9],
                           (const float*)d_in[13]};
  const float* bias[3] = {(const float*)d_in[6], (const float*)d_in[10],
                          (const float*)d_in[14]};

  const int N = in_sizes[0] / 512;  // 20000
  const int E = in_sizes[1];        // 320000
  const int Kdim[3] = {512, 128, 128};
  const int Mdim[3] = {512, 512, 256};

  char* ws = (char*)d_ws;
  size_t o = 0;
  auto alloc = [&](size_t bytes) {
    void* p = ws + o;
    o += (bytes + 15) & ~(size_t)15;
    return p;
  };
  _Float16* fs = (_Float16*)alloc((size_t)N * 512 * 2);
  _Float16* fd = (_Float16*)alloc((size_t)N * 512 * 2);
  _Float16* A0 = (_Float16*)alloc((size_t)N * 512 * 2);
  _Float16* h1 = (_Float16*)alloc((size_t)N * 128 * 2);
  _Float16* h2 = (_Float16*)alloc((size_t)N * 128 * 2);
  _Float16* WT[6];
  for (int L = 0; L < 3; ++L) {
    size_t sz = (size_t)Kdim[L] * Mdim[L] * 2;
    WT[2 * L] = (_Float16*)alloc(sz);
    WT[2 * L + 1] = (_Float16*)alloc(sz);
  }
  int* counts = (int*)alloc((size_t)N * 4);
  int* pcsrc = (int*)alloc((size_t)N * MAXDEG * 4);

  // ---- node 1: zero counts ----
  hipMemsetAsync(counts, 0, (size_t)N * sizeof(int), stream);

  // ---- node 2: fused preproc (transposes + A0 cvt + dout zero + scatter) --
  {
    PreArgs pa;
    int off = 0;
    for (int L = 0; L < 3; ++L) {
      pa.W[2 * L] = Wl[L];
      pa.W[2 * L + 1] = Wr[L];
      pa.WT[2 * L] = WT[2 * L];
      pa.WT[2 * L + 1] = WT[2 * L + 1];
      pa.wK[2 * L] = pa.wK[2 * L + 1] = Kdim[L];
      pa.wM[2 * L] = pa.wM[2 * L + 1] = Mdim[L];
      pa.wOff[2 * L] = off;
      off += Kdim[L] * Mdim[L];
      pa.wOff[2 * L + 1] = off;
      off += Kdim[L] * Mdim[L];
    }
    pa.wTotal = off;
    pa.nf = n_feat;
    pa.A0 = A0;
    pa.aTotal = N * 512;
    pa.src = src;
    pa.dst = dst;
    pa.counts = counts;
    pa.pcsrc = pcsrc;
    pa.E = E;
    pa.dout = (float*)d_out;
    int total = pa.wTotal + pa.aTotal + 64 + E;
    preproc_kernel<<<(total + 255) / 256, 256, 0, stream>>>(pa);
  }

  const _Float16* Ain[3] = {A0, h1, h2};
  _Float16* WlT[3] = {WT[0], WT[2], WT[4]};
  _Float16* WrT[3] = {WT[1], WT[3], WT[5]};

  const int nStrips = (N + TM - 1) / TM;     // 157
  const int S8 = ((nStrips + 7) / 8) * 8;    // 160

  // ---- nodes 3-8: 3x (gemm, attn) ----
  for (int L = 0; L < 3; ++L) {
    const int K = Kdim[L], M = Mdim[L];
    const int nbx = 2 * M / TN;  // 8 or 4
    const int nbxLog2 = (nbx == 8) ? 3 : 2;
    gemm_mfma_dual_kernel<<<S8 * nbx, 256, 0, stream>>>(
        Ain[L], WlT[L], WrT[L], fs, fd, N, K, M, nStrips, nbxLog2);
    if (L == 0) {
      node_attn_kernel<128, false><<<(N + 3) / 4, 256, 0, stream>>>(
          fs, fd, counts, pcsrc, attnw[0], bias[0], h1, nullptr, N);
    } else if (L == 1) {
      node_attn_kernel<128, false><<<(N + 3) / 4, 256, 0, stream>>>(
          fs, fd, counts, pcsrc, attnw[1], bias[1], h2, nullptr, N);
    } else {
      // persistent 1024 blocks: LDS-accumulated final mean, 65k atomics total
      node_attn_kernel<64, true><<<1024, 256, 0, stream>>>(
          fs, fd, counts, pcsrc, attnw[2], bias[2], nullptr, (float*)d_out, N);
    }
  }
}